// Round 4
// baseline (96.470 us; speedup 1.0000x reference)
//
#include <hip/hip_runtime.h>

#define IN_CH 256
#define OUT_CH 512
#define HW 56
#define NPIX (HW * HW)            // 3136
#define WROW (IN_CH * 9)          // 2304
#define NT 10
#define HB 8
#define NDOT (NT * HB)            // 80
#define SIZE_LIMIT 256
#define EPS 1e-3f

// stage1: waddr tiling (2 channels x 1 table per block) + query role
#define WOTILE 2
#define WBLOCKS ((OUT_CH / WOTILE) * NT)   // 2560
#define S1BLOCKS (WBLOCKS + IN_CH)         // + 256 query blocks

// conv tiling
#define OTILE 8
#define OTILES (SIZE_LIMIT / OTILE)        // 32 worst-case
#define PTILE 256
#define PTILES 13                          // ceil(3136/256)
#define KSPLIT 8
#define KCH (IN_CH / KSPLIT)               // 32

// workspace offsets (4-byte units)
#define Q_OFF       0                            // 256 f
#define QADDR_OFF   256                          // 10 i
#define WADDR_OFF   288                          // 10*512 i
#define SLOT_OFF    (WADDR_OFF + NT * OUT_CH)    // 512 i (slot+1, 0 = inactive)
#define NACT_OFF    (SLOT_OFF + OUT_CH)          // 1 i
#define COMPACT_OFF (NACT_OFF + 32)              // 512 i
#define PART_OFF    16384                        // KSPLIT*SIZE_LIMIT*NPIX f (~25.7 MB)

// ---- 1. fused: weight signatures (blocks 0..2559) + global-avg-pool query ----
__global__ __launch_bounds__(256) void k_stage1(const float* __restrict__ x,
                                                const float* __restrict__ whole_w,
                                                const float* __restrict__ rm_w,
                                                float* __restrict__ wsf,
                                                int* __restrict__ wsi) {
    __shared__ float4 sW4[WOTILE][WROW / 4];  // 18.4 KB
    __shared__ int bits[HB][WOTILE];
    __shared__ float red[256];
    int bid = blockIdx.x, tid = threadIdx.x;

    if (bid < WBLOCKS) {
        // ---- weight-signature role: table dg, channels o0, o0+1 ----
        int opair = bid / NT, dg = bid - opair * NT;
        int o0 = opair * WOTILE;
        const float4* w4 = (const float4*)(whole_w + (size_t)o0 * WROW);
        for (int i = tid; i < WOTILE * (WROW / 4); i += 256)
            sW4[i / (WROW / 4)][i % (WROW / 4)] = w4[i];
        __syncthreads();
        int wid = tid >> 6, lane = tid & 63;
        int d0 = dg * HB + wid * 2;  // this block covers all 8 bits of table dg
        const float4* r0 = (const float4*)(rm_w + (size_t)d0 * WROW);
        const float4* r1 = (const float4*)(rm_w + (size_t)(d0 + 1) * WROW);
        float a00 = 0.f, a01 = 0.f, a10 = 0.f, a11 = 0.f;
        for (int i = lane; i < WROW / 4; i += 64) {  // 9 iters
            float4 v0 = r0[i], v1 = r1[i];
            float4 w0 = sW4[0][i], w1 = sW4[1][i];
            a00 += v0.x * w0.x + v0.y * w0.y + v0.z * w0.z + v0.w * w0.w;
            a01 += v0.x * w1.x + v0.y * w1.y + v0.z * w1.z + v0.w * w1.w;
            a10 += v1.x * w0.x + v1.y * w0.y + v1.z * w0.z + v1.w * w0.w;
            a11 += v1.x * w1.x + v1.y * w1.y + v1.z * w1.z + v1.w * w1.w;
        }
        for (int m = 32; m > 0; m >>= 1) {
            a00 += __shfl_xor(a00, m, 64);
            a01 += __shfl_xor(a01, m, 64);
            a10 += __shfl_xor(a10, m, 64);
            a11 += __shfl_xor(a11, m, 64);
        }
        if (lane == 0) {
            bits[wid * 2][0]     = (a00 > 0.f) ? 1 : 0;
            bits[wid * 2][1]     = (a01 > 0.f) ? 1 : 0;
            bits[wid * 2 + 1][0] = (a10 > 0.f) ? 1 : 0;
            bits[wid * 2 + 1][1] = (a11 > 0.f) ? 1 : 0;
        }
        __syncthreads();
        if (tid < WOTILE) {
            int a = 0;
            #pragma unroll
            for (int h = 0; h < HB; h++) a |= bits[h][tid] << (7 - h);
            wsi[WADDR_OFF + dg * OUT_CH + o0 + tid] = a;
        }
    } else {
        // ---- query role: channel c global-avg-pool ----
        int c = bid - WBLOCKS;
        const float* xc = x + c * NPIX;
        float s = 0.f;
        for (int p = tid; p < NPIX; p += 256) s += xc[p];
        red[tid] = s;
        __syncthreads();
        for (int off = 128; off > 0; off >>= 1) {
            if (tid < off) red[tid] += red[tid + off];
            __syncthreads();
        }
        if (tid == 0) wsf[Q_OFF + c] = red[0] / (float)NPIX;
    }
}

// ---- 2. fused: query signatures + histogram + top-k + compaction ----
__global__ void k_select(const float* __restrict__ rm_q, const float* __restrict__ wsf,
                         int* __restrict__ wsi) {
    int tid = threadIdx.x; // 512
    __shared__ float qs[IN_CH];
    __shared__ int qbits[NDOT];
    __shared__ int qsig[NT];
    __shared__ int hist[OUT_CH];
    __shared__ int sel[OUT_CH];
    if (tid < IN_CH) qs[tid] = wsf[Q_OFF + tid];
    __syncthreads();
    if (tid < NDOT * 4) {
        int d = tid >> 2, part = tid & 3;
        const float* r = rm_q + d * IN_CH + part * 64;
        const float* qq = qs + part * 64;
        float acc = 0.f;
        for (int k = 0; k < 64; k++) acc = fmaf(r[k], qq[k], acc);
        acc += __shfl_xor(acc, 1, 64);
        acc += __shfl_xor(acc, 2, 64);
        if (part == 0) qbits[d] = (acc > 0.f) ? 1 : 0;
    }
    __syncthreads();
    if (tid < NT) {
        int a = 0;
        #pragma unroll
        for (int h = 0; h < HB; h++) a |= qbits[tid * HB + h] << (7 - h);
        qsig[tid] = a;
        wsi[QADDR_OFF + tid] = a;
    }
    __syncthreads();
    int h = 0;
    for (int t = 0; t < NT; t++) h += (wsi[WADDR_OFF + t * OUT_CH + tid] == qsig[t]) ? 1 : 0;
    hist[tid] = h;
    __syncthreads();
    int rank = 0;
    for (int j = 0; j < OUT_CH; j++) {
        int hj = hist[j];
        rank += (hj > h || (hj == h && j < tid)) ? 1 : 0;
    }
    int s = (h > 0 && rank < SIZE_LIMIT) ? 1 : 0;
    sel[tid] = s;
    __syncthreads();
    if (s) {
        int pos = 0;
        for (int j = 0; j < tid; j++) pos += sel[j];
        wsi[COMPACT_OFF + pos] = tid;
        wsi[SLOT_OFF + tid] = pos + 1;
    } else {
        wsi[SLOT_OFF + tid] = 0;
    }
    if (tid == 0) {
        int c = 0;
        for (int j = 0; j < OUT_CH; j++) c += sel[j];
        wsi[NACT_OFF] = c;
    }
}

// ---- 3. sparse conv: 8 channels x 256 pixels x 32 in-ch per block -> partials ----
__global__ __launch_bounds__(256) void k_conv(const float* __restrict__ x,
                                              const float* __restrict__ whole_w,
                                              const int* __restrict__ wsi,
                                              float* __restrict__ wsf) {
    int nact = wsi[NACT_OFF];
    int slot0 = blockIdx.y * OTILE;
    if (slot0 >= nact) return;
    int tid = threadIdx.x;
    int p = blockIdx.x * PTILE + tid;
    bool pv = p < NPIX;
    int pc = pv ? p : 0;
    int oh = pc / HW, ow = pc - oh * HW;

    int offs[9];
    bool msk[9];
    #pragma unroll
    for (int kh = -1; kh <= 1; kh++) {
        #pragma unroll
        for (int kw = -1; kw <= 1; kw++) {
            int t = (kh + 1) * 3 + (kw + 1);
            bool m = (oh + kh >= 0) && (oh + kh < HW) && (ow + kw >= 0) && (ow + kw < HW);
            msk[t] = m;
            offs[t] = m ? kh * HW + kw : 0;
        }
    }

    const float* wb[OTILE];
    bool st[OTILE];
    #pragma unroll
    for (int j = 0; j < OTILE; j++) {
        int s = slot0 + j;
        bool real = s < nact;
        st[j] = real;
        int o = wsi[COMPACT_OFF + (real ? s : slot0)];
        int ou = __builtin_amdgcn_readfirstlane(o);
        wb[j] = whole_w + (size_t)ou * WROW + blockIdx.z * (KCH * 9);
    }

    const float* xb = x + blockIdx.z * (KCH * NPIX) + pc;
    float a[OTILE];
    #pragma unroll
    for (int j = 0; j < OTILE; j++) a[j] = 0.f;

    for (int c = 0; c < KCH; ++c) {
        const float* xc = xb + c * NPIX;
        float xv[9];
        #pragma unroll
        for (int t = 0; t < 9; t++) xv[t] = msk[t] ? xc[offs[t]] : 0.f;
        #pragma unroll
        for (int t = 0; t < 9; t++) {
            int wi = c * 9 + t;
            #pragma unroll
            for (int j = 0; j < OTILE; j++) a[j] = fmaf(xv[t], wb[j][wi], a[j]);
        }
    }
    if (pv) {
        float* pb = wsf + PART_OFF + ((size_t)blockIdx.z * SIZE_LIMIT + slot0) * NPIX + p;
        #pragma unroll
        for (int j = 0; j < OTILE; j++)
            if (st[j]) pb[j * NPIX] = a[j];
    }
}

// ---- 4. combine partials + BN (batch stats) + ReLU; zero inactive ----
__global__ void k_bn(const int* __restrict__ wsi, const float* __restrict__ wsf,
                     const float* __restrict__ gamma, const float* __restrict__ beta,
                     float* __restrict__ y) {
    int o = blockIdx.x, tid = threadIdx.x;
    int sl = wsi[SLOT_OFF + o];
    if (!sl) {
        float4* y4 = (float4*)(y + o * NPIX);
        for (int i = tid; i < NPIX / 4; i += 256) y4[i] = make_float4(0.f, 0.f, 0.f, 0.f);
        return;
    }
    int s = sl - 1;
    const float* pb = wsf + PART_OFF + (size_t)s * NPIX;
    float sum = 0.f, sq = 0.f;
    for (int p = tid; p < NPIX; p += 256) {
        float v = 0.f;
        #pragma unroll
        for (int z = 0; z < KSPLIT; z++) v += pb[(size_t)z * SIZE_LIMIT * NPIX + p];
        y[o * NPIX + p] = v;
        sum += v;
        sq += v * v;
    }
    __shared__ float rs[256], rq[256];
    rs[tid] = sum; rq[tid] = sq;
    __syncthreads();
    for (int off = 128; off > 0; off >>= 1) {
        if (tid < off) { rs[tid] += rs[tid + off]; rq[tid] += rq[tid + off]; }
        __syncthreads();
    }
    float mean = rs[0] / (float)NPIX;
    float var = rq[0] / (float)NPIX - mean * mean;
    float inv = 1.0f / sqrtf(var + EPS);
    float g = gamma[o], b = beta[o];
    for (int p = tid; p < NPIX; p += 256) {
        float v = (y[o * NPIX + p] - mean) * inv * g + b;
        y[o * NPIX + p] = (v > 0.f) ? v : 0.f;
    }
}

extern "C" void kernel_launch(void* const* d_in, const int* in_sizes, int n_in,
                              void* d_out, int out_size, void* d_ws, size_t ws_size,
                              hipStream_t stream) {
    const float* x       = (const float*)d_in[0];
    const float* whole_w = (const float*)d_in[1];
    const float* rm_w    = (const float*)d_in[2];
    const float* rm_q    = (const float*)d_in[3];
    const float* gamma   = (const float*)d_in[4];
    const float* beta    = (const float*)d_in[5];
    float* out = (float*)d_out;
    float* wsf = (float*)d_ws;
    int*   wsi = (int*)d_ws;

    k_stage1<<<S1BLOCKS, 256, 0, stream>>>(x, whole_w, rm_w, wsf, wsi);
    k_select<<<1, OUT_CH, 0, stream>>>(rm_q, wsf, wsi);
    k_conv<<<dim3(PTILES, OTILES, KSPLIT), 256, 0, stream>>>(x, whole_w, wsi, wsf);
    k_bn<<<OUT_CH, 256, 0, stream>>>(wsi, wsf, gamma, beta, out);
}

// Round 5
// 81.006 us; speedup vs baseline: 1.1909x; 1.1909x over previous
//
#include <hip/hip_runtime.h>

#define IN_CH 256
#define OUT_CH 512
#define HW 56
#define NPIX (HW * HW)            // 3136
#define WROW (IN_CH * 9)          // 2304
#define NT 10
#define HB 8
#define NDOT (NT * HB)            // 80
#define SIZE_LIMIT 256
#define EPS 1e-3f

// stage1: waddr tiling (4 channels x 1 table per block) + query role
#define WOTILE 4
#define WBLOCKS ((OUT_CH / WOTILE) * NT)   // 1280
#define S1BLOCKS (WBLOCKS + IN_CH)         // + 256 query blocks

// conv tiling
#define OTILE 4
#define OTILES (SIZE_LIMIT / OTILE)        // 64 worst-case
#define PTILE 256
#define PTILES 13                          // ceil(3136/256)
#define KSPLIT 16
#define KCH (IN_CH / KSPLIT)               // 16

// bn
#define BNITER 13                          // ceil(3136/256)

// workspace offsets (4-byte units)
#define Q_OFF       0                            // 256 f
#define QADDR_OFF   256                          // 10 i
#define WADDR_OFF   288                          // 10*512 i
#define SLOT_OFF    (WADDR_OFF + NT * OUT_CH)    // 512 i (slot+1, 0 = inactive)
#define NACT_OFF    (SLOT_OFF + OUT_CH)          // 1 i
#define COMPACT_OFF (NACT_OFF + 32)              // 512 i
#define PART_OFF    16384                        // KSPLIT*SIZE_LIMIT*NPIX f (~51.4 MB)

// ---- 1. fused: weight signatures (blocks 0..1279) + global-avg-pool query ----
__global__ __launch_bounds__(256) void k_stage1(const float* __restrict__ x,
                                                const float* __restrict__ whole_w,
                                                const float* __restrict__ rm_w,
                                                float* __restrict__ wsf,
                                                int* __restrict__ wsi) {
    __shared__ float4 sW4[WOTILE][WROW / 4];  // 36.9 KB
    __shared__ int bits[HB][WOTILE];
    __shared__ float red[256];
    int bid = blockIdx.x, tid = threadIdx.x;

    if (bid < WBLOCKS) {
        // ---- weight-signature role: table dg, channels o0..o0+3 ----
        int ogrp = bid / NT, dg = bid - ogrp * NT;
        int o0 = ogrp * WOTILE;
        const float4* w4 = (const float4*)(whole_w + (size_t)o0 * WROW);
        for (int i = tid; i < WOTILE * (WROW / 4); i += 256)
            sW4[i / (WROW / 4)][i % (WROW / 4)] = w4[i];
        __syncthreads();
        int wid = tid >> 6, lane = tid & 63;
        int d0 = dg * HB + wid * 2;  // block covers all 8 bits of table dg
        const float4* r0 = (const float4*)(rm_w + (size_t)d0 * WROW);
        const float4* r1 = (const float4*)(rm_w + (size_t)(d0 + 1) * WROW);
        float a0[WOTILE], a1[WOTILE];
        #pragma unroll
        for (int j = 0; j < WOTILE; j++) { a0[j] = 0.f; a1[j] = 0.f; }
        for (int i = lane; i < WROW / 4; i += 64) {  // 9 iters
            float4 v0 = r0[i], v1 = r1[i];
            #pragma unroll
            for (int j = 0; j < WOTILE; j++) {
                float4 w = sW4[j][i];
                a0[j] += v0.x * w.x + v0.y * w.y + v0.z * w.z + v0.w * w.w;
                a1[j] += v1.x * w.x + v1.y * w.y + v1.z * w.z + v1.w * w.w;
            }
        }
        #pragma unroll
        for (int j = 0; j < WOTILE; j++) {
            for (int m = 32; m > 0; m >>= 1) {
                a0[j] += __shfl_xor(a0[j], m, 64);
                a1[j] += __shfl_xor(a1[j], m, 64);
            }
        }
        if (lane == 0) {
            #pragma unroll
            for (int j = 0; j < WOTILE; j++) {
                bits[wid * 2][j]     = (a0[j] > 0.f) ? 1 : 0;
                bits[wid * 2 + 1][j] = (a1[j] > 0.f) ? 1 : 0;
            }
        }
        __syncthreads();
        if (tid < WOTILE) {
            int a = 0;
            #pragma unroll
            for (int h = 0; h < HB; h++) a |= bits[h][tid] << (7 - h);
            wsi[WADDR_OFF + dg * OUT_CH + o0 + tid] = a;
        }
    } else {
        // ---- query role: channel c global-avg-pool ----
        int c = bid - WBLOCKS;
        const float* xc = x + c * NPIX;
        float s = 0.f;
        for (int p = tid; p < NPIX; p += 256) s += xc[p];
        red[tid] = s;
        __syncthreads();
        for (int off = 128; off > 0; off >>= 1) {
            if (tid < off) red[tid] += red[tid + off];
            __syncthreads();
        }
        if (tid == 0) wsf[Q_OFF + c] = red[0] / (float)NPIX;
    }
}

// ---- 2. fused: query signatures + histogram + top-k + compaction ----
__global__ void k_select(const float* __restrict__ rm_q, const float* __restrict__ wsf,
                         int* __restrict__ wsi) {
    int tid = threadIdx.x; // 512
    __shared__ float qs[IN_CH];
    __shared__ int qbits[NDOT];
    __shared__ int qsig[NT];
    __shared__ int hist[OUT_CH];
    __shared__ int sel[OUT_CH];
    if (tid < IN_CH) qs[tid] = wsf[Q_OFF + tid];
    __syncthreads();
    if (tid < NDOT * 4) {
        int d = tid >> 2, part = tid & 3;
        const float* r = rm_q + d * IN_CH + part * 64;
        const float* qq = qs + part * 64;
        float acc = 0.f;
        for (int k = 0; k < 64; k++) acc = fmaf(r[k], qq[k], acc);
        acc += __shfl_xor(acc, 1, 64);
        acc += __shfl_xor(acc, 2, 64);
        if (part == 0) qbits[d] = (acc > 0.f) ? 1 : 0;
    }
    __syncthreads();
    if (tid < NT) {
        int a = 0;
        #pragma unroll
        for (int h = 0; h < HB; h++) a |= qbits[tid * HB + h] << (7 - h);
        qsig[tid] = a;
        wsi[QADDR_OFF + tid] = a;
    }
    __syncthreads();
    int h = 0;
    for (int t = 0; t < NT; t++) h += (wsi[WADDR_OFF + t * OUT_CH + tid] == qsig[t]) ? 1 : 0;
    hist[tid] = h;
    __syncthreads();
    int rank = 0;
    for (int j = 0; j < OUT_CH; j++) {
        int hj = hist[j];
        rank += (hj > h || (hj == h && j < tid)) ? 1 : 0;
    }
    int s = (h > 0 && rank < SIZE_LIMIT) ? 1 : 0;
    sel[tid] = s;
    __syncthreads();
    if (s) {
        int pos = 0;
        for (int j = 0; j < tid; j++) pos += sel[j];
        wsi[COMPACT_OFF + pos] = tid;
        wsi[SLOT_OFF + tid] = pos + 1;
    } else {
        wsi[SLOT_OFF + tid] = 0;
    }
    if (tid == 0) {
        int c = 0;
        for (int j = 0; j < OUT_CH; j++) c += sel[j];
        wsi[NACT_OFF] = c;
    }
}

// ---- 3. sparse conv: 4 channels x 256 pixels x 16 in-ch per block -> partials ----
__global__ __launch_bounds__(256) void k_conv(const float* __restrict__ x,
                                              const float* __restrict__ whole_w,
                                              const int* __restrict__ wsi,
                                              float* __restrict__ wsf) {
    int nact = wsi[NACT_OFF];
    int slot0 = blockIdx.y * OTILE;
    if (slot0 >= nact) return;
    int tid = threadIdx.x;
    int p = blockIdx.x * PTILE + tid;
    bool pv = p < NPIX;
    int pc = pv ? p : 0;
    int oh = pc / HW, ow = pc - oh * HW;

    int offs[9];
    bool msk[9];
    #pragma unroll
    for (int kh = -1; kh <= 1; kh++) {
        #pragma unroll
        for (int kw = -1; kw <= 1; kw++) {
            int t = (kh + 1) * 3 + (kw + 1);
            bool m = (oh + kh >= 0) && (oh + kh < HW) && (ow + kw >= 0) && (ow + kw < HW);
            msk[t] = m;
            offs[t] = m ? kh * HW + kw : 0;
        }
    }

    const float* wb[OTILE];
    bool st[OTILE];
    #pragma unroll
    for (int j = 0; j < OTILE; j++) {
        int s = slot0 + j;
        bool real = s < nact;
        st[j] = real;
        int o = wsi[COMPACT_OFF + (real ? s : slot0)];
        int ou = __builtin_amdgcn_readfirstlane(o);
        wb[j] = whole_w + (size_t)ou * WROW + blockIdx.z * (KCH * 9);
    }

    const float* xb = x + blockIdx.z * (KCH * NPIX) + pc;
    float a[OTILE];
    #pragma unroll
    for (int j = 0; j < OTILE; j++) a[j] = 0.f;

    for (int c = 0; c < KCH; ++c) {
        const float* xc = xb + c * NPIX;
        float xv[9];
        #pragma unroll
        for (int t = 0; t < 9; t++) xv[t] = msk[t] ? xc[offs[t]] : 0.f;
        #pragma unroll
        for (int t = 0; t < 9; t++) {
            int wi = c * 9 + t;
            #pragma unroll
            for (int j = 0; j < OTILE; j++) a[j] = fmaf(xv[t], wb[j][wi], a[j]);
        }
    }
    if (pv) {
        float* pb = wsf + PART_OFF + ((size_t)blockIdx.z * SIZE_LIMIT + slot0) * NPIX + p;
        #pragma unroll
        for (int j = 0; j < OTILE; j++)
            if (st[j]) pb[(size_t)j * NPIX] = a[j];
    }
}

// ---- 4. combine partials + BN (batch stats) + ReLU, register-resident ----
__global__ __launch_bounds__(256) void k_bn(const int* __restrict__ wsi,
                                            const float* __restrict__ wsf,
                                            const float* __restrict__ gamma,
                                            const float* __restrict__ beta,
                                            float* __restrict__ y) {
    int o = blockIdx.x, tid = threadIdx.x;
    int sl = wsi[SLOT_OFF + o];
    if (!sl) {
        float4* y4 = (float4*)(y + o * NPIX);
        for (int i = tid; i < NPIX / 4; i += 256) y4[i] = make_float4(0.f, 0.f, 0.f, 0.f);
        return;
    }
    int s = sl - 1;
    const float* pb = wsf + PART_OFF + (size_t)s * NPIX;
    float v[BNITER];
    float sum = 0.f, sq = 0.f;
    #pragma unroll
    for (int i = 0; i < BNITER; i++) {
        int p = tid + i * 256;
        float acc = 0.f;
        if (p < NPIX) {
            #pragma unroll
            for (int z = 0; z < KSPLIT; z++)
                acc += pb[(size_t)z * SIZE_LIMIT * NPIX + p];
        }
        v[i] = acc;
        sum += acc;
        sq += acc * acc;
    }
    __shared__ float rs[256], rq[256];
    rs[tid] = sum; rq[tid] = sq;
    __syncthreads();
    for (int off = 128; off > 0; off >>= 1) {
        if (tid < off) { rs[tid] += rs[tid + off]; rq[tid] += rq[tid + off]; }
        __syncthreads();
    }
    float mean = rs[0] / (float)NPIX;
    float var = rq[0] / (float)NPIX - mean * mean;
    float inv = 1.0f / sqrtf(var + EPS);
    float g = gamma[o], b = beta[o];
    #pragma unroll
    for (int i = 0; i < BNITER; i++) {
        int p = tid + i * 256;
        if (p < NPIX) {
            float t = (v[i] - mean) * inv * g + b;
            y[o * NPIX + p] = (t > 0.f) ? t : 0.f;
        }
    }
}

extern "C" void kernel_launch(void* const* d_in, const int* in_sizes, int n_in,
                              void* d_out, int out_size, void* d_ws, size_t ws_size,
                              hipStream_t stream) {
    const float* x       = (const float*)d_in[0];
    const float* whole_w = (const float*)d_in[1];
    const float* rm_w    = (const float*)d_in[2];
    const float* rm_q    = (const float*)d_in[3];
    const float* gamma   = (const float*)d_in[4];
    const float* beta    = (const float*)d_in[5];
    float* out = (float*)d_out;
    float* wsf = (float*)d_ws;
    int*   wsi = (int*)d_ws;

    k_stage1<<<S1BLOCKS, 256, 0, stream>>>(x, whole_w, rm_w, wsf, wsi);
    k_select<<<1, OUT_CH, 0, stream>>>(rm_q, wsf, wsi);
    k_conv<<<dim3(PTILES, OTILES, KSPLIT), 256, 0, stream>>>(x, whole_w, wsi, wsf);
    k_bn<<<OUT_CH, 256, 0, stream>>>(wsi, wsf, gamma, beta, out);
}

// Round 6
// 68.589 us; speedup vs baseline: 1.4065x; 1.1810x over previous
//
#include <hip/hip_runtime.h>

#define IN_CH 256
#define OUT_CH 512
#define HW 56
#define NPIX (HW * HW)            // 3136
#define NPIX4 (NPIX / 4)          // 784
#define WROW (IN_CH * 9)          // 2304
#define NT 10
#define HB 8
#define NDOT (NT * HB)            // 80
#define SIZE_LIMIT 256
#define EPS 1e-3f

// stage1: waddr tiling (2 channels x 1 table per block) + query role
#define WOTILE 2
#define WBLOCKS ((OUT_CH / WOTILE) * NT)   // 2560
#define S1BLOCKS (WBLOCKS + IN_CH)         // 2816

// conv tiling
#define OTILE 4
#define OTILES (SIZE_LIMIT / OTILE)        // 64 worst-case
#define PTILE 256
#define PTILES 13                          // ceil(3136/256)
#define KSPLIT 16
#define KCH (IN_CH / KSPLIT)               // 16

// combine tiling: 256 thr x float4 = 1024 px per block
#define CTILES 4                           // ceil(3136/1024)

// workspace offsets (4-byte units)
#define Q_OFF       0                            // 256 f
#define QADDR_OFF   256                          // 10 i
#define WADDR_OFF   288                          // 10*512 i
#define SLOT_OFF    (WADDR_OFF + NT * OUT_CH)    // 512 i (slot+1, 0 = inactive)
#define NACT_OFF    (SLOT_OFF + OUT_CH)          // 1 i
#define COMPACT_OFF (NACT_OFF + 32)              // 512 i
#define SSUM_OFF    8192                         // SIZE_LIMIT*CTILES f
#define SSQ_OFF     (SSUM_OFF + SIZE_LIMIT * CTILES)
#define PART_OFF    16384                        // KSPLIT*SIZE_LIMIT*NPIX f (~51.4 MB)

// ---- 1. fused: weight signatures (blocks 0..2559) + global-avg-pool query ----
__global__ __launch_bounds__(256) void k_stage1(const float* __restrict__ x,
                                                const float* __restrict__ whole_w,
                                                const float* __restrict__ rm_w,
                                                float* __restrict__ wsf,
                                                int* __restrict__ wsi) {
    __shared__ float4 sW4[WOTILE][WROW / 4];  // 18.4 KB
    __shared__ int bits[HB][WOTILE];
    __shared__ float red[256];
    int bid = blockIdx.x, tid = threadIdx.x;

    if (bid < WBLOCKS) {
        int opair = bid / NT, dg = bid - opair * NT;
        int o0 = opair * WOTILE;
        const float4* w4 = (const float4*)(whole_w + (size_t)o0 * WROW);
        for (int i = tid; i < WOTILE * (WROW / 4); i += 256)
            sW4[i / (WROW / 4)][i % (WROW / 4)] = w4[i];
        __syncthreads();
        int wid = tid >> 6, lane = tid & 63;
        int d0 = dg * HB + wid * 2;  // block covers all 8 bits of table dg
        const float4* r0 = (const float4*)(rm_w + (size_t)d0 * WROW);
        const float4* r1 = (const float4*)(rm_w + (size_t)(d0 + 1) * WROW);
        float a00 = 0.f, a01 = 0.f, a10 = 0.f, a11 = 0.f;
        for (int i = lane; i < WROW / 4; i += 64) {  // 9 iters
            float4 v0 = r0[i], v1 = r1[i];
            float4 w0 = sW4[0][i], w1 = sW4[1][i];
            a00 += v0.x * w0.x + v0.y * w0.y + v0.z * w0.z + v0.w * w0.w;
            a01 += v0.x * w1.x + v0.y * w1.y + v0.z * w1.z + v0.w * w1.w;
            a10 += v1.x * w0.x + v1.y * w0.y + v1.z * w0.z + v1.w * w0.w;
            a11 += v1.x * w1.x + v1.y * w1.y + v1.z * w1.z + v1.w * w1.w;
        }
        for (int m = 32; m > 0; m >>= 1) {
            a00 += __shfl_xor(a00, m, 64);
            a01 += __shfl_xor(a01, m, 64);
            a10 += __shfl_xor(a10, m, 64);
            a11 += __shfl_xor(a11, m, 64);
        }
        if (lane == 0) {
            bits[wid * 2][0]     = (a00 > 0.f) ? 1 : 0;
            bits[wid * 2][1]     = (a01 > 0.f) ? 1 : 0;
            bits[wid * 2 + 1][0] = (a10 > 0.f) ? 1 : 0;
            bits[wid * 2 + 1][1] = (a11 > 0.f) ? 1 : 0;
        }
        __syncthreads();
        if (tid < WOTILE) {
            int a = 0;
            #pragma unroll
            for (int h = 0; h < HB; h++) a |= bits[h][tid] << (7 - h);
            wsi[WADDR_OFF + dg * OUT_CH + o0 + tid] = a;
        }
    } else {
        int c = bid - WBLOCKS;
        const float* xc = x + c * NPIX;
        float s = 0.f;
        for (int p = tid; p < NPIX; p += 256) s += xc[p];
        red[tid] = s;
        __syncthreads();
        for (int off = 128; off > 0; off >>= 1) {
            if (tid < off) red[tid] += red[tid + off];
            __syncthreads();
        }
        if (tid == 0) wsf[Q_OFF + c] = red[0] / (float)NPIX;
    }
}

// ---- 2. fused: query signatures + histogram + top-k + compaction ----
__global__ void k_select(const float* __restrict__ rm_q, const float* __restrict__ wsf,
                         int* __restrict__ wsi) {
    int tid = threadIdx.x; // 512
    __shared__ float qs[IN_CH];
    __shared__ int qbits[NDOT];
    __shared__ int qsig[NT];
    __shared__ int hist[OUT_CH];
    __shared__ int sel[OUT_CH];
    if (tid < IN_CH) qs[tid] = wsf[Q_OFF + tid];
    __syncthreads();
    if (tid < NDOT * 4) {
        int d = tid >> 2, part = tid & 3;
        const float* r = rm_q + d * IN_CH + part * 64;
        const float* qq = qs + part * 64;
        float acc = 0.f;
        for (int k = 0; k < 64; k++) acc = fmaf(r[k], qq[k], acc);
        acc += __shfl_xor(acc, 1, 64);
        acc += __shfl_xor(acc, 2, 64);
        if (part == 0) qbits[d] = (acc > 0.f) ? 1 : 0;
    }
    __syncthreads();
    if (tid < NT) {
        int a = 0;
        #pragma unroll
        for (int h = 0; h < HB; h++) a |= qbits[tid * HB + h] << (7 - h);
        qsig[tid] = a;
        wsi[QADDR_OFF + tid] = a;
    }
    __syncthreads();
    int h = 0;
    for (int t = 0; t < NT; t++) h += (wsi[WADDR_OFF + t * OUT_CH + tid] == qsig[t]) ? 1 : 0;
    hist[tid] = h;
    __syncthreads();
    int rank = 0;
    for (int j = 0; j < OUT_CH; j++) {
        int hj = hist[j];
        rank += (hj > h || (hj == h && j < tid)) ? 1 : 0;
    }
    int s = (h > 0 && rank < SIZE_LIMIT) ? 1 : 0;
    sel[tid] = s;
    __syncthreads();
    if (s) {
        int pos = 0;
        for (int j = 0; j < tid; j++) pos += sel[j];
        wsi[COMPACT_OFF + pos] = tid;
        wsi[SLOT_OFF + tid] = pos + 1;
    } else {
        wsi[SLOT_OFF + tid] = 0;
    }
    if (tid == 0) {
        int c = 0;
        for (int j = 0; j < OUT_CH; j++) c += sel[j];
        wsi[NACT_OFF] = c;
    }
}

// ---- 3. sparse conv: 4 channels x 256 pixels x 16 in-ch per block -> partials ----
__global__ __launch_bounds__(256) void k_conv(const float* __restrict__ x,
                                              const float* __restrict__ whole_w,
                                              const int* __restrict__ wsi,
                                              float* __restrict__ wsf) {
    int nact = wsi[NACT_OFF];
    int slot0 = blockIdx.y * OTILE;
    if (slot0 >= nact) return;
    int tid = threadIdx.x;
    int p = blockIdx.x * PTILE + tid;
    bool pv = p < NPIX;
    int pc = pv ? p : 0;
    int oh = pc / HW, ow = pc - oh * HW;

    int offs[9];
    bool msk[9];
    #pragma unroll
    for (int kh = -1; kh <= 1; kh++) {
        #pragma unroll
        for (int kw = -1; kw <= 1; kw++) {
            int t = (kh + 1) * 3 + (kw + 1);
            bool m = (oh + kh >= 0) && (oh + kh < HW) && (ow + kw >= 0) && (ow + kw < HW);
            msk[t] = m;
            offs[t] = m ? kh * HW + kw : 0;
        }
    }

    const float* wb[OTILE];
    bool st[OTILE];
    #pragma unroll
    for (int j = 0; j < OTILE; j++) {
        int s = slot0 + j;
        bool real = s < nact;
        st[j] = real;
        int o = wsi[COMPACT_OFF + (real ? s : slot0)];
        int ou = __builtin_amdgcn_readfirstlane(o);
        wb[j] = whole_w + (size_t)ou * WROW + blockIdx.z * (KCH * 9);
    }

    const float* xb = x + blockIdx.z * (KCH * NPIX) + pc;
    float a[OTILE];
    #pragma unroll
    for (int j = 0; j < OTILE; j++) a[j] = 0.f;

    for (int c = 0; c < KCH; ++c) {
        const float* xc = xb + c * NPIX;
        float xv[9];
        #pragma unroll
        for (int t = 0; t < 9; t++) xv[t] = msk[t] ? xc[offs[t]] : 0.f;
        #pragma unroll
        for (int t = 0; t < 9; t++) {
            int wi = c * 9 + t;
            #pragma unroll
            for (int j = 0; j < OTILE; j++) a[j] = fmaf(xv[t], wb[j][wi], a[j]);
        }
    }
    if (pv) {
        float* pb = wsf + PART_OFF + ((size_t)blockIdx.z * SIZE_LIMIT + slot0) * NPIX + p;
        #pragma unroll
        for (int j = 0; j < OTILE; j++)
            if (st[j]) pb[(size_t)j * NPIX] = a[j];
    }
}

// ---- 4. combine K-split partials -> unnormalized y + per-(slot,tile) stats ----
__global__ __launch_bounds__(256) void k_comb(const int* __restrict__ wsi,
                                              const float* __restrict__ wsf,
                                              float* __restrict__ wso,
                                              float* __restrict__ y) {
    int nact = wsi[NACT_OFF];
    int s = blockIdx.y;
    if (s >= nact) return;
    int tile = blockIdx.x, tid = threadIdx.x;
    int o = wsi[COMPACT_OFF + s];
    int i4 = tile * 256 + tid;   // float4 index, 0..783
    float sum = 0.f, sq = 0.f;
    if (i4 < NPIX4) {
        const float4* pb = (const float4*)(wsf + PART_OFF + (size_t)s * NPIX) + i4;
        float4 v = make_float4(0.f, 0.f, 0.f, 0.f);
        #pragma unroll
        for (int z = 0; z < KSPLIT; z++) {
            float4 t = pb[(size_t)z * SIZE_LIMIT * NPIX4];
            v.x += t.x; v.y += t.y; v.z += t.z; v.w += t.w;
        }
        ((float4*)(y + (size_t)o * NPIX))[i4] = v;
        sum = v.x + v.y + v.z + v.w;
        sq = v.x * v.x + v.y * v.y + v.z * v.z + v.w * v.w;
    }
    __shared__ float rs[256], rq[256];
    rs[tid] = sum; rq[tid] = sq;
    __syncthreads();
    for (int off = 128; off > 0; off >>= 1) {
        if (tid < off) { rs[tid] += rs[tid + off]; rq[tid] += rq[tid + off]; }
        __syncthreads();
    }
    if (tid == 0) {
        wso[SSUM_OFF + s * CTILES + tile] = rs[0];
        wso[SSQ_OFF + s * CTILES + tile] = rq[0];
    }
}

// ---- 5. finalize: BN (batch stats) + ReLU in place; zero inactive ----
__global__ __launch_bounds__(256) void k_fin(const int* __restrict__ wsi,
                                             const float* __restrict__ wsf,
                                             const float* __restrict__ gamma,
                                             const float* __restrict__ beta,
                                             float* __restrict__ y) {
    int o = blockIdx.x, tid = threadIdx.x;
    int sl = wsi[SLOT_OFF + o];
    float4* y4 = (float4*)(y + (size_t)o * NPIX);
    if (!sl) {
        for (int i = tid; i < NPIX4; i += 256) y4[i] = make_float4(0.f, 0.f, 0.f, 0.f);
        return;
    }
    int s = sl - 1;
    float sum = 0.f, sq = 0.f;
    #pragma unroll
    for (int t = 0; t < CTILES; t++) {
        sum += wsf[SSUM_OFF + s * CTILES + t];
        sq  += wsf[SSQ_OFF + s * CTILES + t];
    }
    float mean = sum / (float)NPIX;
    float var = sq / (float)NPIX - mean * mean;
    float inv = 1.0f / sqrtf(var + EPS);
    float g = gamma[o], b = beta[o];
    float scale = inv * g;
    float shift = b - mean * scale;
    for (int i = tid; i < NPIX4; i += 256) {
        float4 v = y4[i];
        v.x = fmaf(v.x, scale, shift); v.x = (v.x > 0.f) ? v.x : 0.f;
        v.y = fmaf(v.y, scale, shift); v.y = (v.y > 0.f) ? v.y : 0.f;
        v.z = fmaf(v.z, scale, shift); v.z = (v.z > 0.f) ? v.z : 0.f;
        v.w = fmaf(v.w, scale, shift); v.w = (v.w > 0.f) ? v.w : 0.f;
        y4[i] = v;
    }
}

extern "C" void kernel_launch(void* const* d_in, const int* in_sizes, int n_in,
                              void* d_out, int out_size, void* d_ws, size_t ws_size,
                              hipStream_t stream) {
    const float* x       = (const float*)d_in[0];
    const float* whole_w = (const float*)d_in[1];
    const float* rm_w    = (const float*)d_in[2];
    const float* rm_q    = (const float*)d_in[3];
    const float* gamma   = (const float*)d_in[4];
    const float* beta    = (const float*)d_in[5];
    float* out = (float*)d_out;
    float* wsf = (float*)d_ws;
    int*   wsi = (int*)d_ws;

    k_stage1<<<S1BLOCKS, 256, 0, stream>>>(x, whole_w, rm_w, wsf, wsi);
    k_select<<<1, OUT_CH, 0, stream>>>(rm_q, wsf, wsi);
    k_conv<<<dim3(PTILES, OTILES, KSPLIT), 256, 0, stream>>>(x, whole_w, wsi, wsf);
    k_comb<<<dim3(CTILES, SIZE_LIMIT), 256, 0, stream>>>(wsi, wsf, wsf, out);
    k_fin<<<OUT_CH, 256, 0, stream>>>(wsi, wsf, gamma, beta, out);
}

// Round 7
// 65.912 us; speedup vs baseline: 1.4636x; 1.0406x over previous
//
#include <hip/hip_runtime.h>

#define IN_CH 256
#define OUT_CH 512
#define HW 56
#define NPIX (HW * HW)            // 3136
#define NPIX4 (NPIX / 4)          // 784
#define WROW (IN_CH * 9)          // 2304
#define NT 10
#define HB 8
#define NDOT (NT * HB)            // 80
#define SIZE_LIMIT 256
#define EPS 1e-3f

// stage1 roles: weight-sig blocks + query blocks + y-zero blocks
#define WOTILE 2
#define WBLOCKS ((OUT_CH / WOTILE) * NT)   // 2560
#define QBLOCKS IN_CH                      // 256
#define ZBLOCKS OUT_CH                     // 512
#define S1BLOCKS (WBLOCKS + QBLOCKS + ZBLOCKS)  // 3328

// conv tiling
#define OTILE 4
#define OTILES (SIZE_LIMIT / OTILE)        // 64 worst-case
#define PTILE 256
#define PTILES 13                          // ceil(3136/256)
#define KSPLIT 16
#define KCH (IN_CH / KSPLIT)               // 16
#define WLDS (OTILE * KCH * 9)             // 576 floats

// workspace offsets (4-byte units)
#define Q_OFF       0                            // 256 f
#define QADDR_OFF   256                          // 10 i
#define WADDR_OFF   288                          // 10*512 i
#define SLOT_OFF    (WADDR_OFF + NT * OUT_CH)    // 512 i (slot+1, 0 = inactive)
#define NACT_OFF    (SLOT_OFF + OUT_CH)          // 1 i
#define COMPACT_OFF (NACT_OFF + 32)              // 512 i

// ---- 1. fused: weight signatures + global-avg-pool query + zero y ----
__global__ __launch_bounds__(256) void k_stage1(const float* __restrict__ x,
                                                const float* __restrict__ whole_w,
                                                const float* __restrict__ rm_w,
                                                float* __restrict__ wsf,
                                                int* __restrict__ wsi,
                                                float* __restrict__ y) {
    __shared__ float4 sW4[WOTILE][WROW / 4];  // 18.4 KB
    __shared__ int bits[HB][WOTILE];
    __shared__ float red[256];
    int bid = blockIdx.x, tid = threadIdx.x;

    if (bid < WBLOCKS) {
        // ---- weight-signature role: table dg, channels o0, o0+1 ----
        int opair = bid / NT, dg = bid - opair * NT;
        int o0 = opair * WOTILE;
        const float4* w4 = (const float4*)(whole_w + (size_t)o0 * WROW);
        for (int i = tid; i < WOTILE * (WROW / 4); i += 256)
            sW4[i / (WROW / 4)][i % (WROW / 4)] = w4[i];
        __syncthreads();
        int wid = tid >> 6, lane = tid & 63;
        int d0 = dg * HB + wid * 2;  // block covers all 8 bits of table dg
        const float4* r0 = (const float4*)(rm_w + (size_t)d0 * WROW);
        const float4* r1 = (const float4*)(rm_w + (size_t)(d0 + 1) * WROW);
        float a00 = 0.f, a01 = 0.f, a10 = 0.f, a11 = 0.f;
        for (int i = lane; i < WROW / 4; i += 64) {  // 9 iters
            float4 v0 = r0[i], v1 = r1[i];
            float4 w0 = sW4[0][i], w1 = sW4[1][i];
            a00 += v0.x * w0.x + v0.y * w0.y + v0.z * w0.z + v0.w * w0.w;
            a01 += v0.x * w1.x + v0.y * w1.y + v0.z * w1.z + v0.w * w1.w;
            a10 += v1.x * w0.x + v1.y * w0.y + v1.z * w0.z + v1.w * w0.w;
            a11 += v1.x * w1.x + v1.y * w1.y + v1.z * w1.z + v1.w * w1.w;
        }
        for (int m = 32; m > 0; m >>= 1) {
            a00 += __shfl_xor(a00, m, 64);
            a01 += __shfl_xor(a01, m, 64);
            a10 += __shfl_xor(a10, m, 64);
            a11 += __shfl_xor(a11, m, 64);
        }
        if (lane == 0) {
            bits[wid * 2][0]     = (a00 > 0.f) ? 1 : 0;
            bits[wid * 2][1]     = (a01 > 0.f) ? 1 : 0;
            bits[wid * 2 + 1][0] = (a10 > 0.f) ? 1 : 0;
            bits[wid * 2 + 1][1] = (a11 > 0.f) ? 1 : 0;
        }
        __syncthreads();
        if (tid < WOTILE) {
            int a = 0;
            #pragma unroll
            for (int h = 0; h < HB; h++) a |= bits[h][tid] << (7 - h);
            wsi[WADDR_OFF + dg * OUT_CH + o0 + tid] = a;
        }
    } else if (bid < WBLOCKS + QBLOCKS) {
        // ---- query role: channel c global-avg-pool ----
        int c = bid - WBLOCKS;
        const float* xc = x + c * NPIX;
        float s = 0.f;
        for (int p = tid; p < NPIX; p += 256) s += xc[p];
        red[tid] = s;
        __syncthreads();
        for (int off = 128; off > 0; off >>= 1) {
            if (tid < off) red[tid] += red[tid + off];
            __syncthreads();
        }
        if (tid == 0) wsf[Q_OFF + c] = red[0] / (float)NPIX;
    } else {
        // ---- zero role: one output channel ----
        int o = bid - WBLOCKS - QBLOCKS;
        float4* y4 = (float4*)(y + (size_t)o * NPIX);
        for (int i = tid; i < NPIX4; i += 256) y4[i] = make_float4(0.f, 0.f, 0.f, 0.f);
    }
}

// ---- 2. fused: query signatures + histogram + top-k + compaction ----
__global__ void k_select(const float* __restrict__ rm_q, const float* __restrict__ wsf,
                         int* __restrict__ wsi) {
    int tid = threadIdx.x; // 512
    __shared__ float qs[IN_CH];
    __shared__ int qbits[NDOT];
    __shared__ int qsig[NT];
    __shared__ int hist[OUT_CH];
    __shared__ int sel[OUT_CH];
    if (tid < IN_CH) qs[tid] = wsf[Q_OFF + tid];
    __syncthreads();
    if (tid < NDOT * 4) {
        int d = tid >> 2, part = tid & 3;
        const float* r = rm_q + d * IN_CH + part * 64;
        const float* qq = qs + part * 64;
        float acc = 0.f;
        for (int k = 0; k < 64; k++) acc = fmaf(r[k], qq[k], acc);
        acc += __shfl_xor(acc, 1, 64);
        acc += __shfl_xor(acc, 2, 64);
        if (part == 0) qbits[d] = (acc > 0.f) ? 1 : 0;
    }
    __syncthreads();
    if (tid < NT) {
        int a = 0;
        #pragma unroll
        for (int h = 0; h < HB; h++) a |= qbits[tid * HB + h] << (7 - h);
        qsig[tid] = a;
        wsi[QADDR_OFF + tid] = a;
    }
    __syncthreads();
    int h = 0;
    for (int t = 0; t < NT; t++) h += (wsi[WADDR_OFF + t * OUT_CH + tid] == qsig[t]) ? 1 : 0;
    hist[tid] = h;
    __syncthreads();
    int rank = 0;
    for (int j = 0; j < OUT_CH; j++) {
        int hj = hist[j];
        rank += (hj > h || (hj == h && j < tid)) ? 1 : 0;
    }
    int s = (h > 0 && rank < SIZE_LIMIT) ? 1 : 0;
    sel[tid] = s;
    __syncthreads();
    if (s) {
        int pos = 0;
        for (int j = 0; j < tid; j++) pos += sel[j];
        wsi[COMPACT_OFF + pos] = tid;
        wsi[SLOT_OFF + tid] = pos + 1;
    } else {
        wsi[SLOT_OFF + tid] = 0;
    }
    if (tid == 0) {
        int c = 0;
        for (int j = 0; j < OUT_CH; j++) c += sel[j];
        wsi[NACT_OFF] = c;
    }
}

// ---- 3. sparse conv: LDS weights, atomicAdd into pre-zeroed y ----
__global__ __launch_bounds__(256) void k_conv(const float* __restrict__ x,
                                              const float* __restrict__ whole_w,
                                              const int* __restrict__ wsi,
                                              float* __restrict__ y) {
    int nact = wsi[NACT_OFF];
    int slot0 = blockIdx.y * OTILE;
    if (slot0 >= nact) return;
    int tid = threadIdx.x;

    // resolve the 4 output channels; stage their K-slice weights in LDS
    __shared__ float sWl[OTILE][KCH * 9];   // 2.3 KB
    __shared__ int och[OTILE];
    if (tid < OTILE) {
        int s = slot0 + tid;
        och[tid] = (s < nact) ? wsi[COMPACT_OFF + s] : -1;
    }
    __syncthreads();
    for (int i = tid; i < WLDS; i += 256) {
        int j = i / (KCH * 9), wi = i - j * (KCH * 9);
        int o = (och[j] >= 0) ? och[j] : och[0];
        sWl[j][wi] = whole_w[(size_t)o * WROW + blockIdx.z * (KCH * 9) + wi];
    }
    __syncthreads();

    int p = blockIdx.x * PTILE + tid;
    bool pv = p < NPIX;
    int pc = pv ? p : 0;
    int oh = pc / HW, ow = pc - oh * HW;

    int offs[9];
    bool msk[9];
    #pragma unroll
    for (int kh = -1; kh <= 1; kh++) {
        #pragma unroll
        for (int kw = -1; kw <= 1; kw++) {
            int t = (kh + 1) * 3 + (kw + 1);
            bool m = (oh + kh >= 0) && (oh + kh < HW) && (ow + kw >= 0) && (ow + kw < HW);
            msk[t] = m;
            offs[t] = m ? kh * HW + kw : 0;
        }
    }

    const float* xb = x + blockIdx.z * (KCH * NPIX) + pc;
    float a[OTILE];
    #pragma unroll
    for (int j = 0; j < OTILE; j++) a[j] = 0.f;

    for (int c = 0; c < KCH; ++c) {
        const float* xc = xb + c * NPIX;
        float xv[9];
        #pragma unroll
        for (int t = 0; t < 9; t++) xv[t] = msk[t] ? xc[offs[t]] : 0.f;
        #pragma unroll
        for (int t = 0; t < 9; t++) {
            int wi = c * 9 + t;
            #pragma unroll
            for (int j = 0; j < OTILE; j++) a[j] = fmaf(xv[t], sWl[j][wi], a[j]);
        }
    }
    if (pv) {
        #pragma unroll
        for (int j = 0; j < OTILE; j++)
            if (och[j] >= 0) atomicAdd(&y[(size_t)och[j] * NPIX + p], a[j]);
    }
}

// ---- 4. finalize: stats + BN (batch stats) + ReLU in place, active slots only ----
__global__ __launch_bounds__(256) void k_fin(const int* __restrict__ wsi,
                                             const float* __restrict__ gamma,
                                             const float* __restrict__ beta,
                                             float* __restrict__ y) {
    int s = blockIdx.x, tid = threadIdx.x;
    if (s >= wsi[NACT_OFF]) return;
    int o = wsi[COMPACT_OFF + s];
    float4* y4 = (float4*)(y + (size_t)o * NPIX);
    float sum = 0.f, sq = 0.f;
    for (int i = tid; i < NPIX4; i += 256) {
        float4 v = y4[i];
        sum += v.x + v.y + v.z + v.w;
        sq += v.x * v.x + v.y * v.y + v.z * v.z + v.w * v.w;
    }
    __shared__ float rs[256], rq[256];
    rs[tid] = sum; rq[tid] = sq;
    __syncthreads();
    for (int off = 128; off > 0; off >>= 1) {
        if (tid < off) { rs[tid] += rs[tid + off]; rq[tid] += rq[tid + off]; }
        __syncthreads();
    }
    float mean = rs[0] / (float)NPIX;
    float var = rq[0] / (float)NPIX - mean * mean;
    float inv = 1.0f / sqrtf(var + EPS);
    float g = gamma[o], b = beta[o];
    float scale = inv * g;
    float shift = b - mean * scale;
    for (int i = tid; i < NPIX4; i += 256) {
        float4 v = y4[i];
        v.x = fmaf(v.x, scale, shift); v.x = (v.x > 0.f) ? v.x : 0.f;
        v.y = fmaf(v.y, scale, shift); v.y = (v.y > 0.f) ? v.y : 0.f;
        v.z = fmaf(v.z, scale, shift); v.z = (v.z > 0.f) ? v.z : 0.f;
        v.w = fmaf(v.w, scale, shift); v.w = (v.w > 0.f) ? v.w : 0.f;
        y4[i] = v;
    }
}

extern "C" void kernel_launch(void* const* d_in, const int* in_sizes, int n_in,
                              void* d_out, int out_size, void* d_ws, size_t ws_size,
                              hipStream_t stream) {
    const float* x       = (const float*)d_in[0];
    const float* whole_w = (const float*)d_in[1];
    const float* rm_w    = (const float*)d_in[2];
    const float* rm_q    = (const float*)d_in[3];
    const float* gamma   = (const float*)d_in[4];
    const float* beta    = (const float*)d_in[5];
    float* out = (float*)d_out;
    float* wsf = (float*)d_ws;
    int*   wsi = (int*)d_ws;

    k_stage1<<<S1BLOCKS, 256, 0, stream>>>(x, whole_w, rm_w, wsf, wsi, out);
    k_select<<<1, OUT_CH, 0, stream>>>(rm_q, wsf, wsi);
    k_conv<<<dim3(PTILES, OTILES, KSPLIT), 256, 0, stream>>>(x, whole_w, wsi, out);
    k_fin<<<SIZE_LIMIT, 256, 0, stream>>>(wsi, gamma, beta, out);
}